// Round 1
// baseline (514.074 us; speedup 1.0000x reference)
//
#include <hip/hip_runtime.h>

#define NDET 50      // detections per image
#define BN   100     // B*N
#define NC   80      // classes
#define MM   28      // mask size
#define IMH  800
#define IMW  1333
#define HW   (IMH * IMW)

struct Params {
    float ylo, yhi, xlo, xhi;   // conservative coverage bounds (pixel-center coords)
    float y0, x0, dh, dw;       // box origin + extents (exact f32 as reference computes)
    float score;
    int   base;                 // offset of selected 28x28 plane in mask_outs
};

// One-block setup: per-detection params + scores/class_ids tail of d_out.
__global__ void det2mask_setup(const float* __restrict__ boxes,
                               const float* __restrict__ scores,
                               const int*   __restrict__ class_ids,
                               Params* __restrict__ ps,
                               float* __restrict__ out_tail) {
#pragma clang fp contract(off)
    int i = threadIdx.x;
    if (i < BN) {
        float x0 = boxes[i * 4 + 0];
        float y0 = boxes[i * 4 + 1];
        float x1 = boxes[i * 4 + 2];
        float y1 = boxes[i * 4 + 3];
        float dw = x1 - x0;   // same op order as reference (x1-x0), exact
        float dh = y1 - y0;
        Params p;
        p.y0 = y0; p.x0 = x0; p.dh = dh; p.dw = dw;
        // support of nonzero bilinear output is iy in (-1, 28): py in
        // (y0 - dh/56, y0 + dh + dh/56). Add 1px slack -> strictly conservative.
        p.ylo = y0 - dh * (0.5f / 28.0f) - 1.0f;
        p.yhi = y1 + dh * (0.5f / 28.0f) + 1.0f;
        p.xlo = x0 - dw * (0.5f / 28.0f) - 1.0f;
        p.xhi = x1 + dw * (0.5f / 28.0f) + 1.0f;
        p.score = scores[i];
        int cls = class_ids[i];
        p.base = (i * NC + cls) * (MM * MM);
        ps[i] = p;
        out_tail[i]      = scores[i];       // output 1: scores passthrough
        out_tail[BN + i] = (float)cls;      // output 2: class_ids as float
    }
}

// One thread per pixel (b,y,x): find highest-scoring covering detection,
// then write all NDET mask values for this pixel (coalesced dword stores).
__global__ __launch_bounds__(256) void det2mask_main(
        const float* __restrict__ mask_outs,
        const Params* __restrict__ ps,
        float* __restrict__ out) {
#pragma clang fp contract(off)
    __shared__ Params sp[NDET];
    const int b = blockIdx.z;
    {   // cooperative LDS stage of this batch's 50 param structs (500 dwords)
        const int* src = (const int*)(ps + b * NDET);
        int* dst = (int*)sp;
        for (int i = threadIdx.x; i < NDET * 10; i += 256) dst[i] = src[i];
    }
    __syncthreads();

    const int x = blockIdx.x * 256 + threadIdx.x;
    const int y = blockIdx.y;
    const float px = (float)x + 0.5f;
    const float py = (float)y + 0.5f;

    int best = -1;
    float bs = -1.0f;

    for (int n = 0; n < NDET; ++n) {
        // wave-uniform row reject
        if (py <= sp[n].ylo || py >= sp[n].yhi) continue;
        // per-lane column reject
        if (px <= sp[n].xlo || px >= sp[n].xhi) continue;

        // ---- exact reference arithmetic (f32, no contraction) ----
        float gy = (py - sp[n].y0) / sp[n].dh * 2.0f - 1.0f;
        float iy = ((gy + 1.0f) * 28.0f - 1.0f) / 2.0f;
        float fy = floorf(iy);
        float wy = iy - fy;
        int iy0 = (int)fy;

        float gx = (px - sp[n].x0) / sp[n].dw * 2.0f - 1.0f;
        float ix = ((gx + 1.0f) * 28.0f - 1.0f) / 2.0f;
        float fx = floorf(ix);
        float wx = ix - fx;
        int ix0 = (int)fx;

        const float* mp = mask_outs + sp[n].base;
        int yc0 = min(max(iy0, 0), MM - 1);
        int yc1 = min(max(iy0 + 1, 0), MM - 1);
        int xc0 = min(max(ix0, 0), MM - 1);
        int xc1 = min(max(ix0 + 1, 0), MM - 1);
        bool r0 = (iy0 >= 0) && (iy0 <= MM - 1);
        bool r1 = (iy0 >= -1) && (iy0 <= MM - 2);
        bool c0 = (ix0 >= 0) && (ix0 <= MM - 1);
        bool c1 = (ix0 >= -1) && (ix0 <= MM - 2);

        float v00 = (r0 && c0) ? mp[yc0 * MM + xc0] : 0.0f;
        float v10 = (r1 && c0) ? mp[yc1 * MM + xc0] : 0.0f;
        float v01 = (r0 && c1) ? mp[yc0 * MM + xc1] : 0.0f;
        float v11 = (r1 && c1) ? mp[yc1 * MM + xc1] : 0.0f;

        // identical order to reference: rows-lerp then cols-lerp
        float rr0 = v00 * (1.0f - wy) + v10 * wy;
        float rr1 = v01 * (1.0f - wy) + v11 * wy;
        float val = rr0 * (1.0f - wx) + rr1 * wx;

        if (val >= 0.5f && sp[n].score > bs) { bs = sp[n].score; best = n; }
    }

    if (x < IMW) {
        float* op = out + (size_t)b * NDET * HW + (size_t)y * IMW + x;
        for (int n = 0; n < NDET; ++n) {
            op[(size_t)n * HW] = (n == best) ? 1.0f : 0.0f;
        }
    }
}

extern "C" void kernel_launch(void* const* d_in, const int* in_sizes, int n_in,
                              void* d_out, int out_size, void* d_ws, size_t ws_size,
                              hipStream_t stream) {
    const float* mask_outs = (const float*)d_in[0];
    const float* boxes     = (const float*)d_in[1];
    const float* scores    = (const float*)d_in[2];
    const int*   class_ids = (const int*)d_in[3];
    float* out = (float*)d_out;
    Params* ps = (Params*)d_ws;

    hipLaunchKernelGGL(det2mask_setup, dim3(1), dim3(128), 0, stream,
                       boxes, scores, class_ids, ps, out + (size_t)BN * HW);

    dim3 grid((IMW + 255) / 256, IMH, 2);
    hipLaunchKernelGGL(det2mask_main, grid, dim3(256), 0, stream,
                       mask_outs, ps, out);
}

// Round 2
// 513.455 us; speedup vs baseline: 1.0012x; 1.0012x over previous
//
#include <hip/hip_runtime.h>

#define NDET 50      // detections per image
#define BN   100     // B*N
#define NC   80      // classes
#define MM   28      // mask size
#define IMH  800
#define IMW  1333
#define HW   (IMH * IMW)

struct Params {
    float ylo, yhi, xlo, xhi;   // conservative coverage bounds (pixel-center coords)
    float y0, x0, dh, dw;       // box origin + extents (exact f32 as reference computes)
    float score;
    int   base;                 // offset of selected 28x28 plane in mask_outs
};

// One-block setup: per-detection params + scores/class_ids tail of d_out.
__global__ void det2mask_setup(const float* __restrict__ boxes,
                               const float* __restrict__ scores,
                               const int*   __restrict__ class_ids,
                               Params* __restrict__ ps,
                               float* __restrict__ out_tail) {
#pragma clang fp contract(off)
    int i = threadIdx.x;
    if (i < BN) {
        float x0 = boxes[i * 4 + 0];
        float y0 = boxes[i * 4 + 1];
        float x1 = boxes[i * 4 + 2];
        float y1 = boxes[i * 4 + 3];
        float dw = x1 - x0;   // same op order as reference, exact
        float dh = y1 - y0;
        Params p;
        p.y0 = y0; p.x0 = x0; p.dh = dh; p.dw = dw;
        p.ylo = y0 - dh * (0.5f / 28.0f) - 1.0f;
        p.yhi = y1 + dh * (0.5f / 28.0f) + 1.0f;
        p.xlo = x0 - dw * (0.5f / 28.0f) - 1.0f;
        p.xhi = x1 + dw * (0.5f / 28.0f) + 1.0f;
        p.score = scores[i];
        int cls = class_ids[i];
        p.base = (i * NC + cls) * (MM * MM);
        ps[i] = p;
        out_tail[i]      = scores[i];       // output 1: scores passthrough
        out_tail[BN + i] = (float)cls;      // output 2: class_ids as float
    }
}

// Block = (rowsegment of quads, y, b). Wave 0 compacts row-surviving detections
// (y-dependent terms precomputed) into LDS; each thread then resolves 4 px and
// writes 50 float4 stores (16B-aligned via per-row quad-grid shift).
__global__ __launch_bounds__(128) void det2mask_main(
        const float* __restrict__ mask_outs,
        const Params* __restrict__ ps,
        float* __restrict__ out) {
#pragma clang fp contract(off)
    __shared__ float s_xlo[NDET], s_xhi[NDET], s_x0[NDET], s_dw[NDET];
    __shared__ float s_sc[NDET], s_wy[NDET];
    __shared__ int   s_rb0[NDET], s_rb1[NDET], s_n[NDET];
    __shared__ int   s_ns;

    const int b = blockIdx.z;
    const int y = blockIdx.y;
    const float py = (float)y + 0.5f;
    const int tid = threadIdx.x;

    if (tid < 64) {
        bool cov = false;
        Params p;
        if (tid < NDET) {
            p = ps[b * NDET + tid];
            cov = (py > p.ylo) && (py < p.yhi);
        }
        unsigned long long m = __ballot(cov);
        if (cov) {
            int pos = __popcll(m & ((1ull << tid) - 1ull));
            // ---- exact reference y-arithmetic (f32, no contraction) ----
            float gy = (py - p.y0) / p.dh * 2.0f - 1.0f;
            float iy = ((gy + 1.0f) * 28.0f - 1.0f) / 2.0f;
            float fy = floorf(iy);
            float wy = iy - fy;
            int iy0 = (int)fy;
            bool r0 = (iy0 >= 0) && (iy0 <= MM - 1);
            bool r1 = (iy0 >= -1) && (iy0 <= MM - 2);
            int yc0 = min(max(iy0, 0), MM - 1);
            int yc1 = min(max(iy0 + 1, 0), MM - 1);
            s_xlo[pos] = p.xlo; s_xhi[pos] = p.xhi;
            s_x0[pos] = p.x0;   s_dw[pos] = p.dw;
            s_sc[pos] = p.score; s_wy[pos] = wy;
            s_rb0[pos] = r0 ? (p.base + yc0 * MM) : -1;
            s_rb1[pos] = r1 ? (p.base + yc1 * MM) : -1;
            s_n[pos] = tid;
        }
        if (tid == 0) s_ns = __popcll(m);
    }
    __syncthreads();

    const int ns = s_ns;
    // per-row quad-grid shift so dwordx4 stores are 16B-aligned
    const int sOff = (4 - (y & 3)) & 3;
    const int nq = (IMW - sOff) >> 2;
    const int t = blockIdx.x * 128 + tid;

    int xs, cnt;
    bool vec = false;
    if (t < nq)            { xs = sOff + 4 * t;  cnt = 4;         vec = true; }
    else if (t == nq)      { xs = sOff + 4 * nq; cnt = IMW - xs;  }           // tail <=3
    else if (t == nq + 1)  { xs = 0;             cnt = sOff;      }           // prefix <=3
    else                   { xs = 0;             cnt = 0;         }

    int best[4] = {-1, -1, -1, -1};
    if (cnt > 0) {
        float bs[4] = {-1.0f, -1.0f, -1.0f, -1.0f};
        const float qlo = (float)xs + 0.5f;
        const float qhi = (float)(xs + cnt - 1) + 0.5f;
        for (int s2 = 0; s2 < ns; ++s2) {
            float xlo = s_xlo[s2], xhi = s_xhi[s2];
            if (qhi <= xlo || qlo >= xhi) continue;   // quad-level x reject
            float x0 = s_x0[s2], dw = s_dw[s2];
            float wy = s_wy[s2], sc = s_sc[s2];
            int rb0 = s_rb0[s2], rb1 = s_rb1[s2];
            int n = s_n[s2];
#pragma unroll
            for (int k = 0; k < 4; ++k) {
                if (k >= cnt) break;
                float px = (float)(xs + k) + 0.5f;
                if (px <= xlo || px >= xhi) continue;
                // ---- exact reference x-arithmetic ----
                float gx = (px - x0) / dw * 2.0f - 1.0f;
                float ix = ((gx + 1.0f) * 28.0f - 1.0f) / 2.0f;
                float fx = floorf(ix);
                float wx = ix - fx;
                int ix0 = (int)fx;
                bool c0 = (ix0 >= 0) && (ix0 <= MM - 1);
                bool c1 = (ix0 >= -1) && (ix0 <= MM - 2);
                int xc0 = min(max(ix0, 0), MM - 1);
                int xc1 = min(max(ix0 + 1, 0), MM - 1);
                float v00 = (rb0 >= 0 && c0) ? mask_outs[rb0 + xc0] : 0.0f;
                float v10 = (rb1 >= 0 && c0) ? mask_outs[rb1 + xc0] : 0.0f;
                float v01 = (rb0 >= 0 && c1) ? mask_outs[rb0 + xc1] : 0.0f;
                float v11 = (rb1 >= 0 && c1) ? mask_outs[rb1 + xc1] : 0.0f;
                float rr0 = v00 * (1.0f - wy) + v10 * wy;
                float rr1 = v01 * (1.0f - wy) + v11 * wy;
                float val = rr0 * (1.0f - wx) + rr1 * wx;
                if (val >= 0.5f && sc > bs[k]) { bs[k] = sc; best[k] = n; }
            }
        }
    }

    if (cnt > 0) {
        float* op = out + (size_t)b * NDET * HW + (size_t)y * IMW + xs;
        if (vec) {
            for (int n = 0; n < NDET; ++n) {
                float4 v;
                v.x = (best[0] == n) ? 1.0f : 0.0f;
                v.y = (best[1] == n) ? 1.0f : 0.0f;
                v.z = (best[2] == n) ? 1.0f : 0.0f;
                v.w = (best[3] == n) ? 1.0f : 0.0f;
                *reinterpret_cast<float4*>(op) = v;
                op += HW;
            }
        } else {
            for (int n = 0; n < NDET; ++n) {
#pragma unroll
                for (int k = 0; k < 3; ++k) {
                    if (k < cnt) op[k] = (best[k] == n) ? 1.0f : 0.0f;
                }
                op += HW;
            }
        }
    }
}

extern "C" void kernel_launch(void* const* d_in, const int* in_sizes, int n_in,
                              void* d_out, int out_size, void* d_ws, size_t ws_size,
                              hipStream_t stream) {
    const float* mask_outs = (const float*)d_in[0];
    const float* boxes     = (const float*)d_in[1];
    const float* scores    = (const float*)d_in[2];
    const int*   class_ids = (const int*)d_in[3];
    float* out = (float*)d_out;
    Params* ps = (Params*)d_ws;

    hipLaunchKernelGGL(det2mask_setup, dim3(1), dim3(128), 0, stream,
                       boxes, scores, class_ids, ps, out + (size_t)BN * HW);

    // 3 blocks x 128 threads cover max 333 quads + tail + prefix per row
    dim3 grid(3, IMH, 2);
    hipLaunchKernelGGL(det2mask_main, grid, dim3(128), 0, stream,
                       mask_outs, ps, out);
}

// Round 3
// 451.024 us; speedup vs baseline: 1.1398x; 1.1384x over previous
//
#include <hip/hip_runtime.h>

#define NDET 50      // detections per image
#define BN   100     // B*N
#define NC   80      // classes
#define MM   28      // mask size
#define IMH  800
#define IMW  1333
#define HW   (IMH * IMW)          // 1,066,400
#define NQ_PLANE (HW / 4)         // 266,600 quads per plane

struct Params {
    float ylo, yhi, xlo, xhi;   // conservative coverage bounds (pixel-center coords)
    float y0, x0, dh, dw;       // exact f32 as reference computes
    float score;
    int   base;                 // offset of selected 28x28 plane in mask_outs
};

// One-block setup: per-detection params + scores/class_ids tail of d_out.
__global__ void det2mask_setup(const float* __restrict__ boxes,
                               const float* __restrict__ scores,
                               const int*   __restrict__ class_ids,
                               Params* __restrict__ ps,
                               float* __restrict__ out_tail) {
#pragma clang fp contract(off)
    int i = threadIdx.x;
    if (i < BN) {
        float x0 = boxes[i * 4 + 0];
        float y0 = boxes[i * 4 + 1];
        float x1 = boxes[i * 4 + 2];
        float y1 = boxes[i * 4 + 3];
        float dw = x1 - x0;   // same op order as reference, exact
        float dh = y1 - y0;
        Params p;
        p.y0 = y0; p.x0 = x0; p.dh = dh; p.dw = dw;
        p.ylo = y0 - dh * (0.5f / 28.0f) - 1.0f;
        p.yhi = y1 + dh * (0.5f / 28.0f) + 1.0f;
        p.xlo = x0 - dw * (0.5f / 28.0f) - 1.0f;
        p.xhi = x1 + dw * (0.5f / 28.0f) + 1.0f;
        p.score = scores[i];
        int cls = class_ids[i];
        p.base = (i * NC + cls) * (MM * MM);
        ps[i] = p;
        out_tail[i]      = scores[i];       // output 1: scores passthrough
        out_tail[BN + i] = (float)cls;      // output 2: class_ids as float
    }
}

// Phase A: one block per (row y, image b). Wave 0 compacts row-covering
// detections (y-terms precomputed) into LDS; each thread resolves 4 px and
// stores the winning detection index as one byte each (0xFF = none).
__global__ __launch_bounds__(384) void det2mask_best(
        const float* __restrict__ mask_outs,
        const Params* __restrict__ ps,
        unsigned char* __restrict__ best8) {
#pragma clang fp contract(off)
    __shared__ float s_xlo[NDET], s_xhi[NDET], s_x0[NDET], s_dw[NDET];
    __shared__ float s_sc[NDET], s_wy[NDET];
    __shared__ int   s_rb0[NDET], s_rb1[NDET], s_n[NDET];
    __shared__ int   s_ns;

    const int b = blockIdx.z;
    const int y = blockIdx.y;
    const float py = (float)y + 0.5f;
    const int tid = threadIdx.x;

    if (tid < 64) {
        bool cov = false;
        Params p;
        if (tid < NDET) {
            p = ps[b * NDET + tid];
            cov = (py > p.ylo) && (py < p.yhi);
        }
        unsigned long long m = __ballot(cov);
        if (cov) {
            int pos = __popcll(m & ((1ull << tid) - 1ull));
            // ---- exact reference y-arithmetic (f32, no contraction) ----
            float gy = (py - p.y0) / p.dh * 2.0f - 1.0f;
            float iy = ((gy + 1.0f) * 28.0f - 1.0f) / 2.0f;
            float fy = floorf(iy);
            float wy = iy - fy;
            int iy0 = (int)fy;
            bool r0 = (iy0 >= 0) && (iy0 <= MM - 1);
            bool r1 = (iy0 >= -1) && (iy0 <= MM - 2);
            int yc0 = min(max(iy0, 0), MM - 1);
            int yc1 = min(max(iy0 + 1, 0), MM - 1);
            s_xlo[pos] = p.xlo; s_xhi[pos] = p.xhi;
            s_x0[pos] = p.x0;   s_dw[pos] = p.dw;
            s_sc[pos] = p.score; s_wy[pos] = wy;
            s_rb0[pos] = r0 ? (p.base + yc0 * MM) : -1;
            s_rb1[pos] = r1 ? (p.base + yc1 * MM) : -1;
            s_n[pos] = tid;
        }
        if (tid == 0) s_ns = __popcll(m);
    }
    __syncthreads();

    const int ns = s_ns;
    // per-row quad shift: y*IMW + sOff ≡ 0 (mod 4) since IMW ≡ 1 (mod 4)
    const int sOff = (4 - (y & 3)) & 3;
    const int nq = (IMW - sOff) >> 2;

    int xs, cnt;
    bool vec = false;
    if (tid < nq)            { xs = sOff + 4 * tid; cnt = 4;        vec = true; }
    else if (tid == nq)      { xs = sOff + 4 * nq;  cnt = IMW - xs; }   // tail <=3
    else if (tid == nq + 1)  { xs = 0;              cnt = sOff;     }   // prefix <=3
    else                     { xs = 0;              cnt = 0;        }

    int best[4] = {-1, -1, -1, -1};
    if (cnt > 0) {
        float bs[4] = {-1.0f, -1.0f, -1.0f, -1.0f};
        const float qlo = (float)xs + 0.5f;
        const float qhi = (float)(xs + cnt - 1) + 0.5f;
        for (int s2 = 0; s2 < ns; ++s2) {
            float xlo = s_xlo[s2], xhi = s_xhi[s2];
            if (qhi <= xlo || qlo >= xhi) continue;   // quad-level x reject
            float x0 = s_x0[s2], dw = s_dw[s2];
            float wy = s_wy[s2], sc = s_sc[s2];
            int rb0 = s_rb0[s2], rb1 = s_rb1[s2];
            int n = s_n[s2];
#pragma unroll
            for (int k = 0; k < 4; ++k) {
                if (k >= cnt) break;
                float px = (float)(xs + k) + 0.5f;
                if (px <= xlo || px >= xhi) continue;
                // ---- exact reference x-arithmetic ----
                float gx = (px - x0) / dw * 2.0f - 1.0f;
                float ix = ((gx + 1.0f) * 28.0f - 1.0f) / 2.0f;
                float fx = floorf(ix);
                float wx = ix - fx;
                int ix0 = (int)fx;
                bool c0 = (ix0 >= 0) && (ix0 <= MM - 1);
                bool c1 = (ix0 >= -1) && (ix0 <= MM - 2);
                int xc0 = min(max(ix0, 0), MM - 1);
                int xc1 = min(max(ix0 + 1, 0), MM - 1);
                float v00 = (rb0 >= 0 && c0) ? mask_outs[rb0 + xc0] : 0.0f;
                float v10 = (rb1 >= 0 && c0) ? mask_outs[rb1 + xc0] : 0.0f;
                float v01 = (rb0 >= 0 && c1) ? mask_outs[rb0 + xc1] : 0.0f;
                float v11 = (rb1 >= 0 && c1) ? mask_outs[rb1 + xc1] : 0.0f;
                float rr0 = v00 * (1.0f - wy) + v10 * wy;
                float rr1 = v01 * (1.0f - wy) + v11 * wy;
                float val = rr0 * (1.0f - wx) + rr1 * wx;
                if (val >= 0.5f && sc > bs[k]) { bs[k] = sc; best[k] = n; }
            }
        }
    }

    if (cnt > 0) {
        unsigned char* bp = best8 + (size_t)b * HW + (size_t)y * IMW + xs;
        if (vec) {
            unsigned int v = (unsigned int)(best[0] & 0xFF)
                           | ((unsigned int)(best[1] & 0xFF) << 8)
                           | ((unsigned int)(best[2] & 0xFF) << 16)
                           | ((unsigned int)(best[3] & 0xFF) << 24);
            *reinterpret_cast<unsigned int*>(bp) = v;   // 4B-aligned by sOff
        } else {
#pragma unroll
            for (int k = 0; k < 3; ++k) {
                if (k < cnt) bp[k] = (unsigned char)(best[k] & 0xFF);
            }
        }
    }
}

// Phase B: plane-linear streaming writer (fill-kernel store pattern).
// grid = (261 chunks, 100 planes); thread reads 4 best-bytes (one dword,
// L2-resident) and writes one float4; 4 quads per thread, stride 256.
__global__ __launch_bounds__(256) void det2mask_write(
        const unsigned char* __restrict__ best8,
        float* __restrict__ out) {
    const int pid = blockIdx.y;                 // b*NDET + n, 0..99
    const int b = (pid >= NDET) ? 1 : 0;
    const int n = pid - b * NDET;
    const unsigned int* bp = reinterpret_cast<const unsigned int*>(best8 + (size_t)b * HW);
    float4* op = reinterpret_cast<float4*>(out + (size_t)pid * HW);
    const int q0 = blockIdx.x * 1024 + threadIdx.x;
#pragma unroll
    for (int i = 0; i < 4; ++i) {
        int q = q0 + i * 256;
        if (q < NQ_PLANE) {
            unsigned int v = bp[q];
            float4 f;
            f.x = (((v      ) & 0xFFu) == (unsigned)n) ? 1.0f : 0.0f;
            f.y = (((v >>  8) & 0xFFu) == (unsigned)n) ? 1.0f : 0.0f;
            f.z = (((v >> 16) & 0xFFu) == (unsigned)n) ? 1.0f : 0.0f;
            f.w = (((v >> 24) & 0xFFu) == (unsigned)n) ? 1.0f : 0.0f;
            op[q] = f;
        }
    }
}

extern "C" void kernel_launch(void* const* d_in, const int* in_sizes, int n_in,
                              void* d_out, int out_size, void* d_ws, size_t ws_size,
                              hipStream_t stream) {
    const float* mask_outs = (const float*)d_in[0];
    const float* boxes     = (const float*)d_in[1];
    const float* scores    = (const float*)d_in[2];
    const int*   class_ids = (const int*)d_in[3];
    float* out = (float*)d_out;
    Params* ps = (Params*)d_ws;
    unsigned char* best8 = (unsigned char*)d_ws + 4096;   // 2,132,800 B

    hipLaunchKernelGGL(det2mask_setup, dim3(1), dim3(128), 0, stream,
                       boxes, scores, class_ids, ps, out + (size_t)BN * HW);

    hipLaunchKernelGGL(det2mask_best, dim3(1, IMH, 2), dim3(384), 0, stream,
                       mask_outs, ps, best8);

    dim3 gw((NQ_PLANE + 1023) / 1024, BN);
    hipLaunchKernelGGL(det2mask_write, gw, dim3(256), 0, stream,
                       best8, out);
}

// Round 4
// 448.132 us; speedup vs baseline: 1.1471x; 1.0065x over previous
//
#include <hip/hip_runtime.h>

#define NDET 50      // detections per image
#define BN   100     // B*N
#define NC   80      // classes
#define MM   28      // mask size
#define IMH  800
#define IMW  1333
#define HW   (IMH * IMW)          // 1,066,400
#define NQ_PLANE (HW / 4)         // 266,600 quads per plane

typedef float f32x4 __attribute__((ext_vector_type(4)));

// Phase A (setup fused): one block per (row y, image b). Wave 0 computes all
// 50 detection params from raw inputs (bit-identical ops to the reference),
// compacts row-covering detections into LDS; each thread resolves 4 px and
// stores the winning detection index as one byte each (0xFF = none).
// Block (y=0,b=0) also writes the scores/class_ids tail of d_out.
__global__ __launch_bounds__(384) void det2mask_best(
        const float* __restrict__ mask_outs,
        const float* __restrict__ boxes,
        const float* __restrict__ scores,
        const int*   __restrict__ class_ids,
        unsigned char* __restrict__ best8,
        float* __restrict__ out_tail) {
#pragma clang fp contract(off)
    __shared__ float s_xlo[NDET], s_xhi[NDET], s_x0[NDET], s_dw[NDET];
    __shared__ float s_sc[NDET], s_wy[NDET];
    __shared__ int   s_rb0[NDET], s_rb1[NDET], s_n[NDET];
    __shared__ int   s_ns;

    const int b = blockIdx.z;
    const int y = blockIdx.y;
    const float py = (float)y + 0.5f;
    const int tid = threadIdx.x;

    if (tid < 64) {
        bool cov = false;
        float p_xlo = 0.f, p_xhi = 0.f, p_x0 = 0.f, p_dw = 0.f, p_sc = 0.f;
        float p_y0 = 0.f, p_dh = 0.f;
        int   p_base = 0;
        if (tid < NDET) {
            const int gi = b * NDET + tid;
            float bx0 = boxes[gi * 4 + 0];
            float by0 = boxes[gi * 4 + 1];
            float bx1 = boxes[gi * 4 + 2];
            float by1 = boxes[gi * 4 + 3];
            float dw = bx1 - bx0;   // same op order as reference, exact
            float dh = by1 - by0;
            float ylo = by0 - dh * (0.5f / 28.0f) - 1.0f;
            float yhi = by1 + dh * (0.5f / 28.0f) + 1.0f;
            cov = (py > ylo) && (py < yhi);
            p_xlo = bx0 - dw * (0.5f / 28.0f) - 1.0f;
            p_xhi = bx1 + dw * (0.5f / 28.0f) + 1.0f;
            p_x0 = bx0; p_dw = dw; p_y0 = by0; p_dh = dh;
            p_sc = scores[gi];
            p_base = (gi * NC + class_ids[gi]) * (MM * MM);
        }
        unsigned long long m = __ballot(cov);
        if (cov) {
            int pos = __popcll(m & ((1ull << tid) - 1ull));
            // ---- exact reference y-arithmetic (f32, no contraction) ----
            float gy = (py - p_y0) / p_dh * 2.0f - 1.0f;
            float iy = ((gy + 1.0f) * 28.0f - 1.0f) / 2.0f;
            float fy = floorf(iy);
            float wy = iy - fy;
            int iy0 = (int)fy;
            bool r0 = (iy0 >= 0) && (iy0 <= MM - 1);
            bool r1 = (iy0 >= -1) && (iy0 <= MM - 2);
            int yc0 = min(max(iy0, 0), MM - 1);
            int yc1 = min(max(iy0 + 1, 0), MM - 1);
            s_xlo[pos] = p_xlo; s_xhi[pos] = p_xhi;
            s_x0[pos] = p_x0;   s_dw[pos] = p_dw;
            s_sc[pos] = p_sc;   s_wy[pos] = wy;
            s_rb0[pos] = r0 ? (p_base + yc0 * MM) : -1;
            s_rb1[pos] = r1 ? (p_base + yc1 * MM) : -1;
            s_n[pos] = tid;
        }
        if (tid == 0) s_ns = __popcll(m);
    } else if (y == 0 && b == 0 && tid >= 64 && tid < 64 + BN) {
        // tail outputs: scores passthrough + class_ids as float
        int i = tid - 64;
        out_tail[i]      = scores[i];
        out_tail[BN + i] = (float)class_ids[i];
    }
    __syncthreads();

    const int ns = s_ns;
    // per-row quad shift: y*IMW + sOff ≡ 0 (mod 4) since IMW ≡ 1 (mod 4)
    const int sOff = (4 - (y & 3)) & 3;
    const int nq = (IMW - sOff) >> 2;

    int xs, cnt;
    bool vec = false;
    if (tid < nq)            { xs = sOff + 4 * tid; cnt = 4;        vec = true; }
    else if (tid == nq)      { xs = sOff + 4 * nq;  cnt = IMW - xs; }   // tail <=3
    else if (tid == nq + 1)  { xs = 0;              cnt = sOff;     }   // prefix <=3
    else                     { xs = 0;              cnt = 0;        }

    int best[4] = {-1, -1, -1, -1};
    if (cnt > 0) {
        float bs[4] = {-1.0f, -1.0f, -1.0f, -1.0f};
        const float qlo = (float)xs + 0.5f;
        const float qhi = (float)(xs + cnt - 1) + 0.5f;
        for (int s2 = 0; s2 < ns; ++s2) {
            float xlo = s_xlo[s2], xhi = s_xhi[s2];
            if (qhi <= xlo || qlo >= xhi) continue;   // quad-level x reject
            float x0 = s_x0[s2], dw = s_dw[s2];
            float wy = s_wy[s2], sc = s_sc[s2];
            int rb0 = s_rb0[s2], rb1 = s_rb1[s2];
            int n = s_n[s2];
#pragma unroll
            for (int k = 0; k < 4; ++k) {
                if (k >= cnt) break;
                float px = (float)(xs + k) + 0.5f;
                if (px <= xlo || px >= xhi) continue;
                // ---- exact reference x-arithmetic ----
                float gx = (px - x0) / dw * 2.0f - 1.0f;
                float ix = ((gx + 1.0f) * 28.0f - 1.0f) / 2.0f;
                float fx = floorf(ix);
                float wx = ix - fx;
                int ix0 = (int)fx;
                bool c0 = (ix0 >= 0) && (ix0 <= MM - 1);
                bool c1 = (ix0 >= -1) && (ix0 <= MM - 2);
                int xc0 = min(max(ix0, 0), MM - 1);
                int xc1 = min(max(ix0 + 1, 0), MM - 1);
                float v00 = (rb0 >= 0 && c0) ? mask_outs[rb0 + xc0] : 0.0f;
                float v10 = (rb1 >= 0 && c0) ? mask_outs[rb1 + xc0] : 0.0f;
                float v01 = (rb0 >= 0 && c1) ? mask_outs[rb0 + xc1] : 0.0f;
                float v11 = (rb1 >= 0 && c1) ? mask_outs[rb1 + xc1] : 0.0f;
                float rr0 = v00 * (1.0f - wy) + v10 * wy;
                float rr1 = v01 * (1.0f - wy) + v11 * wy;
                float val = rr0 * (1.0f - wx) + rr1 * wx;
                if (val >= 0.5f && sc > bs[k]) { bs[k] = sc; best[k] = n; }
            }
        }
    }

    if (cnt > 0) {
        unsigned char* bp = best8 + (size_t)b * HW + (size_t)y * IMW + xs;
        if (vec) {
            unsigned int v = (unsigned int)(best[0] & 0xFF)
                           | ((unsigned int)(best[1] & 0xFF) << 8)
                           | ((unsigned int)(best[2] & 0xFF) << 16)
                           | ((unsigned int)(best[3] & 0xFF) << 24);
            *reinterpret_cast<unsigned int*>(bp) = v;   // 4B-aligned by sOff
        } else {
#pragma unroll
            for (int k = 0; k < 3; ++k) {
                if (k < cnt) bp[k] = (unsigned char)(best[k] & 0xFF);
            }
        }
    }
}

// Phase B: plane-linear streaming writer. Nontemporal float4 stores keep the
// 426 MB write stream OUT of L2 so best8 (4.26 MB) stays L2-resident for its
// 100x reuse. Thread reads one best-dword, writes one float4; 4 quads/thread.
__global__ __launch_bounds__(256) void det2mask_write(
        const unsigned char* __restrict__ best8,
        float* __restrict__ out) {
    const int pid = blockIdx.y;                 // b*NDET + n, 0..99
    const int b = (pid >= NDET) ? 1 : 0;
    const int n = pid - b * NDET;
    const unsigned int* bp = reinterpret_cast<const unsigned int*>(best8 + (size_t)b * HW);
    f32x4* op = reinterpret_cast<f32x4*>(out + (size_t)pid * HW);
    const int q0 = blockIdx.x * 1024 + threadIdx.x;
#pragma unroll
    for (int i = 0; i < 4; ++i) {
        int q = q0 + i * 256;
        if (q < NQ_PLANE) {
            unsigned int v = bp[q];
            f32x4 f;
            f.x = (((v      ) & 0xFFu) == (unsigned)n) ? 1.0f : 0.0f;
            f.y = (((v >>  8) & 0xFFu) == (unsigned)n) ? 1.0f : 0.0f;
            f.z = (((v >> 16) & 0xFFu) == (unsigned)n) ? 1.0f : 0.0f;
            f.w = (((v >> 24) & 0xFFu) == (unsigned)n) ? 1.0f : 0.0f;
            __builtin_nontemporal_store(f, op + q);
        }
    }
}

extern "C" void kernel_launch(void* const* d_in, const int* in_sizes, int n_in,
                              void* d_out, int out_size, void* d_ws, size_t ws_size,
                              hipStream_t stream) {
    const float* mask_outs = (const float*)d_in[0];
    const float* boxes     = (const float*)d_in[1];
    const float* scores    = (const float*)d_in[2];
    const int*   class_ids = (const int*)d_in[3];
    float* out = (float*)d_out;
    unsigned char* best8 = (unsigned char*)d_ws;   // 2,132,800 B

    hipLaunchKernelGGL(det2mask_best, dim3(1, IMH, 2), dim3(384), 0, stream,
                       mask_outs, boxes, scores, class_ids, best8,
                       out + (size_t)BN * HW);

    dim3 gw((NQ_PLANE + 1023) / 1024, BN);
    hipLaunchKernelGGL(det2mask_write, gw, dim3(256), 0, stream,
                       best8, out);
}

// Round 5
// 447.656 us; speedup vs baseline: 1.1484x; 1.0011x over previous
//
#include <hip/hip_runtime.h>

#define NDET 50      // detections per image
#define BN   100     // B*N
#define NC   80      // classes
#define MM   28      // mask size
#define IMH  800
#define IMW  1333
#define HW   (IMH * IMW)          // 1,066,400
#define NQ_PLANE (HW / 4)         // 266,600 quads per plane

typedef float f32x4 __attribute__((ext_vector_type(4)));

// Phase A (setup fused): one block per (row y, image b). Wave 0 computes all
// 50 detection params from raw inputs (bit-identical ops to the reference),
// compacts row-covering detections into LDS; each thread resolves 4 px and
// stores the winning detection index as one byte each (0xFF = none).
// Block (y=0,b=0) also writes the scores/class_ids tail of d_out.
__global__ __launch_bounds__(384) void det2mask_best(
        const float* __restrict__ mask_outs,
        const float* __restrict__ boxes,
        const float* __restrict__ scores,
        const int*   __restrict__ class_ids,
        unsigned char* __restrict__ best8,
        float* __restrict__ out_tail) {
#pragma clang fp contract(off)
    __shared__ float s_xlo[NDET], s_xhi[NDET], s_x0[NDET], s_dw[NDET];
    __shared__ float s_sc[NDET], s_wy[NDET];
    __shared__ int   s_rb0[NDET], s_rb1[NDET], s_n[NDET];
    __shared__ int   s_ns;

    const int b = blockIdx.z;
    const int y = blockIdx.y;
    const float py = (float)y + 0.5f;
    const int tid = threadIdx.x;

    if (tid < 64) {
        bool cov = false;
        float p_xlo = 0.f, p_xhi = 0.f, p_x0 = 0.f, p_dw = 0.f, p_sc = 0.f;
        float p_y0 = 0.f, p_dh = 0.f;
        int   p_base = 0;
        if (tid < NDET) {
            const int gi = b * NDET + tid;
            float bx0 = boxes[gi * 4 + 0];
            float by0 = boxes[gi * 4 + 1];
            float bx1 = boxes[gi * 4 + 2];
            float by1 = boxes[gi * 4 + 3];
            float dw = bx1 - bx0;   // same op order as reference, exact
            float dh = by1 - by0;
            float ylo = by0 - dh * (0.5f / 28.0f) - 1.0f;
            float yhi = by1 + dh * (0.5f / 28.0f) + 1.0f;
            cov = (py > ylo) && (py < yhi);
            p_xlo = bx0 - dw * (0.5f / 28.0f) - 1.0f;
            p_xhi = bx1 + dw * (0.5f / 28.0f) + 1.0f;
            p_x0 = bx0; p_dw = dw; p_y0 = by0; p_dh = dh;
            p_sc = scores[gi];
            p_base = (gi * NC + class_ids[gi]) * (MM * MM);
        }
        unsigned long long m = __ballot(cov);
        if (cov) {
            int pos = __popcll(m & ((1ull << tid) - 1ull));
            // ---- exact reference y-arithmetic (f32, no contraction) ----
            float gy = (py - p_y0) / p_dh * 2.0f - 1.0f;
            float iy = ((gy + 1.0f) * 28.0f - 1.0f) / 2.0f;
            float fy = floorf(iy);
            float wy = iy - fy;
            int iy0 = (int)fy;
            bool r0 = (iy0 >= 0) && (iy0 <= MM - 1);
            bool r1 = (iy0 >= -1) && (iy0 <= MM - 2);
            int yc0 = min(max(iy0, 0), MM - 1);
            int yc1 = min(max(iy0 + 1, 0), MM - 1);
            s_xlo[pos] = p_xlo; s_xhi[pos] = p_xhi;
            s_x0[pos] = p_x0;   s_dw[pos] = p_dw;
            s_sc[pos] = p_sc;   s_wy[pos] = wy;
            s_rb0[pos] = r0 ? (p_base + yc0 * MM) : -1;
            s_rb1[pos] = r1 ? (p_base + yc1 * MM) : -1;
            s_n[pos] = tid;
        }
        if (tid == 0) s_ns = __popcll(m);
    } else if (y == 0 && b == 0 && tid >= 64 && tid < 64 + BN) {
        // tail outputs: scores passthrough + class_ids as float
        int i = tid - 64;
        out_tail[i]      = scores[i];
        out_tail[BN + i] = (float)class_ids[i];
    }
    __syncthreads();

    const int ns = s_ns;
    // per-row quad shift: y*IMW + sOff ≡ 0 (mod 4) since IMW ≡ 1 (mod 4)
    const int sOff = (4 - (y & 3)) & 3;
    const int nq = (IMW - sOff) >> 2;

    int xs, cnt;
    bool vec = false;
    if (tid < nq)            { xs = sOff + 4 * tid; cnt = 4;        vec = true; }
    else if (tid == nq)      { xs = sOff + 4 * nq;  cnt = IMW - xs; }   // tail <=3
    else if (tid == nq + 1)  { xs = 0;              cnt = sOff;     }   // prefix <=3
    else                     { xs = 0;              cnt = 0;        }

    int best[4] = {-1, -1, -1, -1};
    if (cnt > 0) {
        float bs[4] = {-1.0f, -1.0f, -1.0f, -1.0f};
        const float qlo = (float)xs + 0.5f;
        const float qhi = (float)(xs + cnt - 1) + 0.5f;
        for (int s2 = 0; s2 < ns; ++s2) {
            float xlo = s_xlo[s2], xhi = s_xhi[s2];
            if (qhi <= xlo || qlo >= xhi) continue;   // quad-level x reject
            float x0 = s_x0[s2], dw = s_dw[s2];
            float wy = s_wy[s2], sc = s_sc[s2];
            int rb0 = s_rb0[s2], rb1 = s_rb1[s2];
            int n = s_n[s2];
#pragma unroll
            for (int k = 0; k < 4; ++k) {
                if (k >= cnt) break;
                float px = (float)(xs + k) + 0.5f;
                if (px <= xlo || px >= xhi) continue;
                // ---- exact reference x-arithmetic ----
                float gx = (px - x0) / dw * 2.0f - 1.0f;
                float ix = ((gx + 1.0f) * 28.0f - 1.0f) / 2.0f;
                float fx = floorf(ix);
                float wx = ix - fx;
                int ix0 = (int)fx;
                bool c0 = (ix0 >= 0) && (ix0 <= MM - 1);
                bool c1 = (ix0 >= -1) && (ix0 <= MM - 2);
                int xc0 = min(max(ix0, 0), MM - 1);
                int xc1 = min(max(ix0 + 1, 0), MM - 1);
                float v00 = (rb0 >= 0 && c0) ? mask_outs[rb0 + xc0] : 0.0f;
                float v10 = (rb1 >= 0 && c0) ? mask_outs[rb1 + xc0] : 0.0f;
                float v01 = (rb0 >= 0 && c1) ? mask_outs[rb0 + xc1] : 0.0f;
                float v11 = (rb1 >= 0 && c1) ? mask_outs[rb1 + xc1] : 0.0f;
                float rr0 = v00 * (1.0f - wy) + v10 * wy;
                float rr1 = v01 * (1.0f - wy) + v11 * wy;
                float val = rr0 * (1.0f - wx) + rr1 * wx;
                if (val >= 0.5f && sc > bs[k]) { bs[k] = sc; best[k] = n; }
            }
        }
    }

    if (cnt > 0) {
        unsigned char* bp = best8 + (size_t)b * HW + (size_t)y * IMW + xs;
        if (vec) {
            unsigned int v = (unsigned int)(best[0] & 0xFF)
                           | ((unsigned int)(best[1] & 0xFF) << 8)
                           | ((unsigned int)(best[2] & 0xFF) << 16)
                           | ((unsigned int)(best[3] & 0xFF) << 24);
            *reinterpret_cast<unsigned int*>(bp) = v;   // 4B-aligned by sOff
        } else {
#pragma unroll
            for (int k = 0; k < 3; ++k) {
                if (k < cnt) bp[k] = (unsigned char)(best[k] & 0xFF);
            }
        }
    }
}

// Phase B: plane-linear streaming writer with bbox skip. A plane's nonzero
// support is confined to detection n's conservative bbox (best==n impossible
// outside phase A's x/y-reject bounds, recomputed here bit-identically with
// a 0.5px margin). Outside it: store zeros, no best8 read (~97% of quads).
__global__ __launch_bounds__(256) void det2mask_write(
        const unsigned char* __restrict__ best8,
        const float* __restrict__ boxes,
        float* __restrict__ out) {
#pragma clang fp contract(off)
    const int pid = blockIdx.y;                 // b*NDET + n, 0..99
    const int b = (pid >= NDET) ? 1 : 0;
    const int n = pid - b * NDET;

    // per-plane conservative cover bounds (block-uniform -> scalar)
    const float bx0 = boxes[pid * 4 + 0];
    const float by0 = boxes[pid * 4 + 1];
    const float bx1 = boxes[pid * 4 + 2];
    const float by1 = boxes[pid * 4 + 3];
    const float dw = bx1 - bx0;
    const float dh = by1 - by0;
    const float xlo = (bx0 - dw * (0.5f / 28.0f) - 1.0f) - 0.5f;  // margin
    const float xhi = (bx1 + dw * (0.5f / 28.0f) + 1.0f) + 0.5f;
    const float ylo = (by0 - dh * (0.5f / 28.0f) - 1.0f) - 0.5f;
    const float yhi = (by1 + dh * (0.5f / 28.0f) + 1.0f) + 0.5f;

    const unsigned int* bp = reinterpret_cast<const unsigned int*>(best8 + (size_t)b * HW);
    f32x4* op = reinterpret_cast<f32x4*>(out + (size_t)pid * HW);
    const int q0 = blockIdx.x * 1024 + threadIdx.x;
#pragma unroll
    for (int i = 0; i < 4; ++i) {
        int q = q0 + i * 256;
        if (q < NQ_PLANE) {
            int p0 = q * 4;
            int y = p0 / IMW;             // magic-mul division
            int x = p0 - y * IMW;
            float fy  = (float)y + 0.5f;
            float fx0 = (float)x + 0.5f;
            float fx3 = (float)(x + 3) + 0.5f;
            bool rowin = (fy > ylo) && (fy < yhi);
            bool in;
            if (x + 3 < IMW) {
                in = rowin && (fx3 > xlo) && (fx0 < xhi);
            } else {
                // quad wraps to next row (rare): conservative row-only test
                float fy1 = fy + 1.0f;
                in = rowin || ((fy1 > ylo) && (fy1 < yhi));
            }
            f32x4 f = {0.0f, 0.0f, 0.0f, 0.0f};
            if (in) {
                unsigned int v = bp[q];
                f.x = (((v      ) & 0xFFu) == (unsigned)n) ? 1.0f : 0.0f;
                f.y = (((v >>  8) & 0xFFu) == (unsigned)n) ? 1.0f : 0.0f;
                f.z = (((v >> 16) & 0xFFu) == (unsigned)n) ? 1.0f : 0.0f;
                f.w = (((v >> 24) & 0xFFu) == (unsigned)n) ? 1.0f : 0.0f;
            }
            __builtin_nontemporal_store(f, op + q);
        }
    }
}

extern "C" void kernel_launch(void* const* d_in, const int* in_sizes, int n_in,
                              void* d_out, int out_size, void* d_ws, size_t ws_size,
                              hipStream_t stream) {
    const float* mask_outs = (const float*)d_in[0];
    const float* boxes     = (const float*)d_in[1];
    const float* scores    = (const float*)d_in[2];
    const int*   class_ids = (const int*)d_in[3];
    float* out = (float*)d_out;
    unsigned char* best8 = (unsigned char*)d_ws;   // 2,132,800 B

    hipLaunchKernelGGL(det2mask_best, dim3(1, IMH, 2), dim3(384), 0, stream,
                       mask_outs, boxes, scores, class_ids, best8,
                       out + (size_t)BN * HW);

    dim3 gw((NQ_PLANE + 1023) / 1024, BN);
    hipLaunchKernelGGL(det2mask_write, gw, dim3(256), 0, stream,
                       best8, boxes, out);
}